// Round 3
// baseline (690.800 us; speedup 1.0000x reference)
//
#include <hip/hip_runtime.h>
#include <math.h>

#define NN 100000          // nodes
#define NE 1600000         // edges
#define KDIM 128           // in_dim
#define ODIM 64            // out_dim
#define NBKT ((NN + 255) / 256)   // 391 buckets of 256 nodes each
#define LBUF 6144                 // per-bucket LDS entry cap (avg 4092, +30 sigma safe)

typedef unsigned int uint;
typedef unsigned short ushort;

static __device__ __forceinline__ ushort f2bf(float f) {
  uint u = __float_as_uint(f);
  uint r = (u + 0x7fffu + ((u >> 16) & 1u)) >> 16;   // RNE
  return (ushort)r;
}
static __device__ __forceinline__ float bf2f(ushort v) {
  return __uint_as_float((uint)v << 16);
}

// ---------------- Kernel A: h = x @ W^T (bf16 out), fused s_src/s_dst ----
__global__ __launch_bounds__(256, 2) void k_h(
    const float* __restrict__ x, const float* __restrict__ W,
    const float* __restrict__ a_src, const float* __restrict__ a_dst,
    ushort* __restrict__ h16, float* __restrict__ ssrc, float* __restrict__ sdst)
{
  __shared__ float4 xs4[64 * 32];
  __shared__ float4 ws4[64 * 32];
  const int tid = threadIdx.x;
  const int ty = tid >> 4;
  const int tx = tid & 15;
  const int base = blockIdx.x * 64;

  const float4* x4 = (const float4*)x;
  const float4* W4 = (const float4*)W;
#pragma unroll
  for (int q = 0; q < 8; ++q) {
    int f = q * 256 + tid;
    int row = f >> 5, c4 = f & 31;
    int sw = row * 32 + (c4 ^ (row & 7));
    ws4[sw] = W4[f];
    int node = base + row;
    float4 xv = make_float4(0.f, 0.f, 0.f, 0.f);
    if (node < NN) xv = x4[node * 32 + c4];
    xs4[sw] = xv;
  }
  __syncthreads();

  float acc[4][4];
#pragma unroll
  for (int i = 0; i < 4; ++i)
#pragma unroll
    for (int j = 0; j < 4; ++j) acc[i][j] = 0.f;

  const int axor = ty & 7, bxor = tx & 7;
  int arow[4], brow[4];
#pragma unroll
  for (int i = 0; i < 4; ++i) { arow[i] = (ty + 16 * i) * 32; brow[i] = (tx + 16 * i) * 32; }

#pragma unroll 8
  for (int k4 = 0; k4 < 32; ++k4) {
    float4 a4[4], b4[4];
#pragma unroll
    for (int i = 0; i < 4; ++i) a4[i] = xs4[arow[i] + (k4 ^ axor)];
#pragma unroll
    for (int j = 0; j < 4; ++j) b4[j] = ws4[brow[j] + (k4 ^ bxor)];
#pragma unroll
    for (int i = 0; i < 4; ++i)
#pragma unroll
      for (int j = 0; j < 4; ++j)
        acc[i][j] += a4[i].x * b4[j].x + a4[i].y * b4[j].y
                   + a4[i].z * b4[j].z + a4[i].w * b4[j].w;
  }

  float as[4], ad[4];
#pragma unroll
  for (int j = 0; j < 4; ++j) { as[j] = a_src[tx + 16 * j]; ad[j] = a_dst[tx + 16 * j]; }
#pragma unroll
  for (int i = 0; i < 4; ++i) {
    float ps = acc[i][0] * as[0] + acc[i][1] * as[1] + acc[i][2] * as[2] + acc[i][3] * as[3];
    float pd = acc[i][0] * ad[0] + acc[i][1] * ad[1] + acc[i][2] * ad[2] + acc[i][3] * ad[3];
#pragma unroll
    for (int m = 1; m < 16; m <<= 1) { ps += __shfl_xor(ps, m); pd += __shfl_xor(pd, m); }
    int node = base + ty + 16 * i;
    if (tx == 0 && node < NN) { ssrc[node] = ps; sdst[node] = pd; }
  }
#pragma unroll
  for (int i = 0; i < 4; ++i) {
    int node = base + ty + 16 * i;
    if (node < NN) {
#pragma unroll
      for (int j = 0; j < 4; ++j) h16[node * 64 + tx + 16 * j] = f2bf(acc[i][j]);
    }
  }
}

// ---------------- bucket histogram (LDS pre-aggregated) ----------------
__global__ __launch_bounds__(256) void k_bhist(const int* __restrict__ ei,
                                               int* __restrict__ bcnt)
{
  __shared__ int hh[NBKT];
  int t = threadIdx.x;
  for (int i = t; i < NBKT; i += 256) hh[i] = 0;
  __syncthreads();
  int base = blockIdx.x * 2048;
#pragma unroll
  for (int q = 0; q < 8; ++q) {
    int e = base + q * 256 + t;
    if (e < NE) atomicAdd(&hh[ei[NE + e] >> 8], 1);
  }
  __syncthreads();
  for (int i = t; i < NBKT; i += 256) if (hh[i]) atomicAdd(&bcnt[i], hh[i]);
}

// ---------------- bucket scan: offsets + cursors, offsets[NN]=NE ------------
__global__ __launch_bounds__(512) void k_bscan(const int* __restrict__ bcnt,
                                               int* __restrict__ boff,
                                               int* __restrict__ bcur,
                                               int* __restrict__ offsets)
{
  __shared__ int sm[512];
  int t = threadIdx.x;
  int v = (t < NBKT) ? bcnt[t] : 0;
  sm[t] = v;
  __syncthreads();
  for (int off = 1; off < 512; off <<= 1) {
    int u = (t >= off) ? sm[t - off] : 0;
    __syncthreads();
    sm[t] += u;
    __syncthreads();
  }
  int excl = sm[t] - v;
  if (t < NBKT) { boff[t] = excl; bcur[t] = excl; }
  if (t == NBKT - 1) boff[NBKT] = excl + v;   // == NE
  if (t == 0) offsets[NN] = NE;
}

// ---------------- bin edges into bucket-contiguous stage (4B packed) --------
__global__ __launch_bounds__(256) void k_bin(const int* __restrict__ ei,
                                             int* __restrict__ bcur,
                                             int* __restrict__ stage)
{
  int e = blockIdx.x * blockDim.x + threadIdx.x;
  if (e >= NE) return;
  int src = ei[e];
  int dst = ei[NE + e];
  int pos = atomicAdd(&bcur[dst >> 8], 1);
  stage[pos] = src | ((dst & 255) << 24);
}

// ---------------- place: per-bucket node-sort in LDS, coalesced CSR out -----
// Also produces the global per-node offsets array.
__global__ __launch_bounds__(256) void k_place(const int* __restrict__ boff,
                                               const int* __restrict__ stage,
                                               const float* __restrict__ ssrc,
                                               const float* __restrict__ sdst,
                                               int* __restrict__ offsets,
                                               int2* __restrict__ csr)
{
  __shared__ int2 lbuf[LBUF];
  __shared__ int cnt[256];
  __shared__ int cur[256];
  __shared__ float sdl[256];
  int b = blockIdx.x, t = threadIdx.x;
  int nb = b << 8;
  int e_beg = boff[b], e_end = boff[b + 1];
  int m = e_end - e_beg;

  cnt[t] = 0;
  int node = nb + t;
  sdl[t] = (node < NN) ? sdst[node] : 0.f;
  __syncthreads();

  for (int i = t; i < m; i += 256)
    atomicAdd(&cnt[((uint)stage[e_beg + i]) >> 24], 1);
  __syncthreads();

  int v0 = cnt[t];
  for (int off = 1; off < 256; off <<= 1) {
    int u = (t >= off) ? cnt[t - off] : 0;
    __syncthreads();
    cnt[t] += u;
    __syncthreads();
  }
  int excl = cnt[t] - v0;
  cur[t] = excl;
  if (node < NN) offsets[node] = e_beg + excl;
  __syncthreads();

  for (int i = t; i < m; i += 256) {
    uint v = (uint)stage[e_beg + i];
    int dl = v >> 24;
    int src = v & 0xFFFFFF;
    int slot = atomicAdd(&cur[dl], 1);
    float e = ssrc[src] + sdl[dl];
    e = (e >= 0.f) ? e : 0.2f * e;
    e = fminf(fmaxf(e, -10.f), 10.f);
    lbuf[slot] = make_int2(src, __float_as_int(__expf(e)));
  }
  __syncthreads();
  for (int i = t; i < m; i += 256) csr[e_beg + i] = lbuf[i];
}

// ---------------- aggregation: 16 lanes/node, 4 nodes/wave, unroll-4 --------
__global__ __launch_bounds__(256) void k_agg(const int* __restrict__ offsets,
                                             const int2* __restrict__ csr,
                                             const ushort* __restrict__ h16,
                                             float* __restrict__ out)
{
  int t = blockIdx.x * 256 + threadIdx.x;
  int node = t >> 4;
  int l4 = t & 15;
  if (node >= NN) return;
  int beg = offsets[node];
  int end = offsets[node + 1];
  const uint2* h2 = (const uint2*)h16;
  float ax = 0.f, ay = 0.f, az = 0.f, aw = 0.f, den = 0.f;
  int last = end - 1;
  for (int j = beg; j < end; j += 4) {
    int2 e0 = csr[j];
    int2 e1 = csr[min(j + 1, last)];
    int2 e2 = csr[min(j + 2, last)];
    int2 e3 = csr[min(j + 3, last)];
    float a0 = __int_as_float(e0.y);
    float a1 = (j + 1 < end) ? __int_as_float(e1.y) : 0.f;
    float a2 = (j + 2 < end) ? __int_as_float(e2.y) : 0.f;
    float a3 = (j + 3 < end) ? __int_as_float(e3.y) : 0.f;
    uint2 q0 = h2[e0.x * 16 + l4];
    uint2 q1 = h2[e1.x * 16 + l4];
    uint2 q2 = h2[e2.x * 16 + l4];
    uint2 q3 = h2[e3.x * 16 + l4];
    den += (a0 + a1) + (a2 + a3);
    ax += a0 * bf2f((ushort)(q0.x & 0xffff)) + a1 * bf2f((ushort)(q1.x & 0xffff))
        + a2 * bf2f((ushort)(q2.x & 0xffff)) + a3 * bf2f((ushort)(q3.x & 0xffff));
    ay += a0 * bf2f((ushort)(q0.x >> 16)) + a1 * bf2f((ushort)(q1.x >> 16))
        + a2 * bf2f((ushort)(q2.x >> 16)) + a3 * bf2f((ushort)(q3.x >> 16));
    az += a0 * bf2f((ushort)(q0.y & 0xffff)) + a1 * bf2f((ushort)(q1.y & 0xffff))
        + a2 * bf2f((ushort)(q2.y & 0xffff)) + a3 * bf2f((ushort)(q3.y & 0xffff));
    aw += a0 * bf2f((ushort)(q0.y >> 16)) + a1 * bf2f((ushort)(q1.y >> 16))
        + a2 * bf2f((ushort)(q2.y >> 16)) + a3 * bf2f((ushort)(q3.y >> 16));
  }
  float inv = 1.f / (den + 1e-9f);
  float4 o;
  o.x = ax * inv; o.y = ay * inv; o.z = az * inv; o.w = aw * inv;
  ((float4*)out)[node * 16 + l4] = o;
}

extern "C" void kernel_launch(void* const* d_in, const int* in_sizes, int n_in,
                              void* d_out, int out_size, void* d_ws, size_t ws_size,
                              hipStream_t stream)
{
  const float* x     = (const float*)d_in[0];
  const int*   ei    = (const int*)d_in[1];
  const float* W     = (const float*)d_in[2];
  const float* a_src = (const float*)d_in[3];
  const float* a_dst = (const float*)d_in[4];
  float* out = (float*)d_out;

  char* p = (char*)d_ws;
  auto alloc = [&](size_t bytes) -> char* {
    char* r = p;
    p += (bytes + 255) & ~(size_t)255;
    return r;
  };
  ushort* h16    = (ushort*)alloc((size_t)NN * 64 * 2);
  float* ssrc    = (float*)alloc((size_t)NN * 4);
  float* sdst    = (float*)alloc((size_t)NN * 4);
  int*   offsets = (int*)alloc((size_t)(NN + 1) * 4);
  int*   bcnt    = (int*)alloc((size_t)(NBKT + 1) * 4);
  int*   boff    = (int*)alloc((size_t)(NBKT + 1) * 4);
  int*   bcur    = (int*)alloc((size_t)(NBKT + 1) * 4);
  int*   stage   = (int*)alloc((size_t)NE * 4);
  int2*  csr     = (int2*)alloc((size_t)NE * 8);

  hipMemsetAsync(bcnt, 0, (size_t)(NBKT + 1) * 4, stream);
  k_h<<<(NN + 63) / 64, 256, 0, stream>>>(x, W, a_src, a_dst, h16, ssrc, sdst);
  k_bhist<<<(NE + 2047) / 2048, 256, 0, stream>>>(ei, bcnt);
  k_bscan<<<1, 512, 0, stream>>>(bcnt, boff, bcur, offsets);
  k_bin<<<(NE + 255) / 256, 256, 0, stream>>>(ei, bcur, stage);
  k_place<<<NBKT, 256, 0, stream>>>(boff, stage, ssrc, sdst, offsets, csr);
  k_agg<<<((size_t)NN * 16 + 255) / 256, 256, 0, stream>>>(offsets, csr, h16, out);
}

// Round 4
// 385.329 us; speedup vs baseline: 1.7928x; 1.7928x over previous
//
#include <hip/hip_runtime.h>
#include <math.h>

#define NN 100000          // nodes
#define NE 1600000         // edges
#define NBKT 391           // buckets of 256 nodes: (NN+255)/256
#define EPB 4096           // edges per partition block
#define NPB ((NE + EPB - 1) / EPB)        // 391 partition blocks
#define TOTC (NBKT * NPB)                 // scanned table size
#define SCAN_T 1024
#define SCAN_E ((TOTC + SCAN_T - 1) / SCAN_T)
#define LBUF 6144          // per-bucket LDS entry cap (mean 4092, +32 sigma)

typedef unsigned int uint;
typedef unsigned short ushort;

static __device__ __forceinline__ ushort f2bf(float f) {
  uint u = __float_as_uint(f);
  uint r = (u + 0x7fffu + ((u >> 16) & 1u)) >> 16;   // RNE
  return (ushort)r;
}
static __device__ __forceinline__ float bf2f(ushort v) {
  return __uint_as_float((uint)v << 16);
}

// ---------------- Kernel A: h = x @ W^T (bf16 out), fused s_src/s_dst ----
__global__ __launch_bounds__(256, 2) void k_h(
    const float* __restrict__ x, const float* __restrict__ W,
    const float* __restrict__ a_src, const float* __restrict__ a_dst,
    ushort* __restrict__ h16, float* __restrict__ ssrc, float* __restrict__ sdst)
{
  __shared__ float4 xs4[64 * 32];
  __shared__ float4 ws4[64 * 32];
  const int tid = threadIdx.x;
  const int ty = tid >> 4;
  const int tx = tid & 15;
  const int base = blockIdx.x * 64;

  const float4* x4 = (const float4*)x;
  const float4* W4 = (const float4*)W;
#pragma unroll
  for (int q = 0; q < 8; ++q) {
    int f = q * 256 + tid;
    int row = f >> 5, c4 = f & 31;
    int sw = row * 32 + (c4 ^ (row & 7));
    ws4[sw] = W4[f];
    int node = base + row;
    float4 xv = make_float4(0.f, 0.f, 0.f, 0.f);
    if (node < NN) xv = x4[node * 32 + c4];
    xs4[sw] = xv;
  }
  __syncthreads();

  float acc[4][4];
#pragma unroll
  for (int i = 0; i < 4; ++i)
#pragma unroll
    for (int j = 0; j < 4; ++j) acc[i][j] = 0.f;

  const int axor = ty & 7, bxor = tx & 7;
  int arow[4], brow[4];
#pragma unroll
  for (int i = 0; i < 4; ++i) { arow[i] = (ty + 16 * i) * 32; brow[i] = (tx + 16 * i) * 32; }

#pragma unroll 8
  for (int k4 = 0; k4 < 32; ++k4) {
    float4 a4[4], b4[4];
#pragma unroll
    for (int i = 0; i < 4; ++i) a4[i] = xs4[arow[i] + (k4 ^ axor)];
#pragma unroll
    for (int j = 0; j < 4; ++j) b4[j] = ws4[brow[j] + (k4 ^ bxor)];
#pragma unroll
    for (int i = 0; i < 4; ++i)
#pragma unroll
      for (int j = 0; j < 4; ++j)
        acc[i][j] += a4[i].x * b4[j].x + a4[i].y * b4[j].y
                   + a4[i].z * b4[j].z + a4[i].w * b4[j].w;
  }

  float as[4], ad[4];
#pragma unroll
  for (int j = 0; j < 4; ++j) { as[j] = a_src[tx + 16 * j]; ad[j] = a_dst[tx + 16 * j]; }
#pragma unroll
  for (int i = 0; i < 4; ++i) {
    float ps = acc[i][0] * as[0] + acc[i][1] * as[1] + acc[i][2] * as[2] + acc[i][3] * as[3];
    float pd = acc[i][0] * ad[0] + acc[i][1] * ad[1] + acc[i][2] * ad[2] + acc[i][3] * ad[3];
#pragma unroll
    for (int m = 1; m < 16; m <<= 1) { ps += __shfl_xor(ps, m); pd += __shfl_xor(pd, m); }
    int node = base + ty + 16 * i;
    if (tx == 0 && node < NN) { ssrc[node] = ps; sdst[node] = pd; }
  }
#pragma unroll
  for (int i = 0; i < 4; ++i) {
    int node = base + ty + 16 * i;
    if (node < NN) {
#pragma unroll
      for (int j = 0; j < 4; ++j) h16[node * 64 + tx + 16 * j] = f2bf(acc[i][j]);
    }
  }
}

// ---------------- per-block bucket histogram (no global atomics) ----------------
__global__ __launch_bounds__(256) void k_hist(const int* __restrict__ ei,
                                              int* __restrict__ cnt)
{
  __shared__ int hh[NBKT];
  int t = threadIdx.x, blk = blockIdx.x;
  for (int i = t; i < NBKT; i += 256) hh[i] = 0;
  __syncthreads();
  int base = blk * EPB;
#pragma unroll
  for (int q = 0; q < EPB / 256; ++q) {
    int e = base + q * 256 + t;
    if (e < NE) atomicAdd(&hh[ei[NE + e] >> 8], 1);
  }
  __syncthreads();
  for (int i = t; i < NBKT; i += 256) cnt[i * NPB + blk] = hh[i];
}

// ---------------- global exclusive scan of cnt[NBKT*NPB] (one block) ------------
__global__ __launch_bounds__(SCAN_T) void k_scan(int* __restrict__ cnt,
                                                 int* __restrict__ boff,
                                                 int* __restrict__ offsets)
{
  __shared__ int sm[SCAN_T];
  int t = threadIdx.x;
  int beg = t * SCAN_E;
  int end = min(beg + SCAN_E, TOTC);
  int tot = 0;
  for (int i = beg; i < end; ++i) tot += cnt[i];
  sm[t] = tot;
  __syncthreads();
  for (int off = 1; off < SCAN_T; off <<= 1) {
    int u = (t >= off) ? sm[t - off] : 0;
    __syncthreads();
    sm[t] += u;
    __syncthreads();
  }
  int run = sm[t] - tot;          // exclusive base for this thread's range
  for (int i = beg; i < end; ++i) {
    int v = cnt[i];
    cnt[i] = run;
    if (i % NPB == 0) boff[i / NPB] = run;
    run += v;
  }
  if (t == 0) { boff[NBKT] = NE; offsets[NN] = NE; }
}

// ---------------- partition pass: LDS cursors, alpha computed inline ------------
__global__ __launch_bounds__(256) void k_part(const int* __restrict__ ei,
                                              const int* __restrict__ cnt,
                                              const float* __restrict__ ssrc,
                                              const float* __restrict__ sdst,
                                              int2* __restrict__ stage)
{
  __shared__ int cur[NBKT];
  int t = threadIdx.x, blk = blockIdx.x;
  for (int i = t; i < NBKT; i += 256) cur[i] = cnt[i * NPB + blk];
  __syncthreads();
  int base = blk * EPB;
#pragma unroll
  for (int q = 0; q < EPB / 256; ++q) {
    int e = base + q * 256 + t;
    if (e < NE) {
      int src = ei[e];
      int dst = ei[NE + e];
      int pos = atomicAdd(&cur[dst >> 8], 1);
      float v = ssrc[src] + sdst[dst];
      v = (v >= 0.f) ? v : 0.2f * v;           // LeakyReLU(0.2)
      v = fminf(fmaxf(v, -10.f), 10.f);        // clip
      stage[pos] = make_int2(src | ((dst & 255) << 24), __float_as_int(__expf(v)));
    }
  }
}

// ---------------- place: per-bucket node-sort in LDS, coalesced CSR out ---------
__global__ __launch_bounds__(256) void k_place(const int* __restrict__ boff,
                                               const int2* __restrict__ stage,
                                               int* __restrict__ offsets,
                                               int2* __restrict__ csr)
{
  __shared__ int2 lbuf[LBUF];
  __shared__ int cnt2[256];
  __shared__ int cur2[256];
  int b = blockIdx.x, t = threadIdx.x;
  int e_beg = boff[b], e_end = boff[b + 1];
  int m = e_end - e_beg;

  cnt2[t] = 0;
  __syncthreads();
  for (int i = t; i < m; i += 256)
    atomicAdd(&cnt2[((uint)stage[e_beg + i].x) >> 24], 1);
  __syncthreads();

  int v0 = cnt2[t];
  for (int off = 1; off < 256; off <<= 1) {
    int u = (t >= off) ? cnt2[t - off] : 0;
    __syncthreads();
    cnt2[t] += u;
    __syncthreads();
  }
  int excl = cnt2[t] - v0;
  cur2[t] = excl;
  int node = (b << 8) + t;
  if (node < NN) offsets[node] = e_beg + excl;
  __syncthreads();

  for (int i = t; i < m; i += 256) {
    int2 v = stage[e_beg + i];
    int dl = ((uint)v.x) >> 24;
    int slot = atomicAdd(&cur2[dl], 1);
    lbuf[slot] = make_int2(v.x & 0xFFFFFF, v.y);
  }
  __syncthreads();
  for (int i = t; i < m; i += 256) csr[e_beg + i] = lbuf[i];
}

// ---------------- aggregation: 16 lanes/node, 4 nodes/wave, unroll-4 ------------
__global__ __launch_bounds__(256) void k_agg(const int* __restrict__ offsets,
                                             const int2* __restrict__ csr,
                                             const ushort* __restrict__ h16,
                                             float* __restrict__ out)
{
  int t = blockIdx.x * 256 + threadIdx.x;
  int node = t >> 4;
  int l4 = t & 15;
  if (node >= NN) return;
  int beg = offsets[node];
  int end = offsets[node + 1];
  const uint2* h2 = (const uint2*)h16;
  float ax = 0.f, ay = 0.f, az = 0.f, aw = 0.f, den = 0.f;
  int last = end - 1;
  for (int j = beg; j < end; j += 4) {
    int2 e0 = csr[j];
    int2 e1 = csr[min(j + 1, last)];
    int2 e2 = csr[min(j + 2, last)];
    int2 e3 = csr[min(j + 3, last)];
    float a0 = __int_as_float(e0.y);
    float a1 = (j + 1 < end) ? __int_as_float(e1.y) : 0.f;
    float a2 = (j + 2 < end) ? __int_as_float(e2.y) : 0.f;
    float a3 = (j + 3 < end) ? __int_as_float(e3.y) : 0.f;
    uint2 q0 = h2[e0.x * 16 + l4];
    uint2 q1 = h2[e1.x * 16 + l4];
    uint2 q2 = h2[e2.x * 16 + l4];
    uint2 q3 = h2[e3.x * 16 + l4];
    den += (a0 + a1) + (a2 + a3);
    ax += a0 * bf2f((ushort)(q0.x & 0xffff)) + a1 * bf2f((ushort)(q1.x & 0xffff))
        + a2 * bf2f((ushort)(q2.x & 0xffff)) + a3 * bf2f((ushort)(q3.x & 0xffff));
    ay += a0 * bf2f((ushort)(q0.x >> 16)) + a1 * bf2f((ushort)(q1.x >> 16))
        + a2 * bf2f((ushort)(q2.x >> 16)) + a3 * bf2f((ushort)(q3.x >> 16));
    az += a0 * bf2f((ushort)(q0.y & 0xffff)) + a1 * bf2f((ushort)(q1.y & 0xffff))
        + a2 * bf2f((ushort)(q2.y & 0xffff)) + a3 * bf2f((ushort)(q3.y & 0xffff));
    aw += a0 * bf2f((ushort)(q0.y >> 16)) + a1 * bf2f((ushort)(q1.y >> 16))
        + a2 * bf2f((ushort)(q2.y >> 16)) + a3 * bf2f((ushort)(q3.y >> 16));
  }
  float inv = 1.f / (den + 1e-9f);
  float4 o;
  o.x = ax * inv; o.y = ay * inv; o.z = az * inv; o.w = aw * inv;
  ((float4*)out)[node * 16 + l4] = o;
}

extern "C" void kernel_launch(void* const* d_in, const int* in_sizes, int n_in,
                              void* d_out, int out_size, void* d_ws, size_t ws_size,
                              hipStream_t stream)
{
  const float* x     = (const float*)d_in[0];
  const int*   ei    = (const int*)d_in[1];
  const float* W     = (const float*)d_in[2];
  const float* a_src = (const float*)d_in[3];
  const float* a_dst = (const float*)d_in[4];
  float* out = (float*)d_out;

  char* p = (char*)d_ws;
  auto alloc = [&](size_t bytes) -> char* {
    char* r = p;
    p += (bytes + 255) & ~(size_t)255;
    return r;
  };
  ushort* h16    = (ushort*)alloc((size_t)NN * 64 * 2);
  float* ssrc    = (float*)alloc((size_t)NN * 4);
  float* sdst    = (float*)alloc((size_t)NN * 4);
  int*   offsets = (int*)alloc((size_t)(NN + 1) * 4);
  int*   cnt     = (int*)alloc((size_t)TOTC * 4);
  int*   boff    = (int*)alloc((size_t)(NBKT + 1) * 4);
  int2*  stage   = (int2*)alloc((size_t)NE * 8);
  int2*  csr     = (int2*)alloc((size_t)NE * 8);

  k_h<<<(NN + 63) / 64, 256, 0, stream>>>(x, W, a_src, a_dst, h16, ssrc, sdst);
  k_hist<<<NPB, 256, 0, stream>>>(ei, cnt);
  k_scan<<<1, SCAN_T, 0, stream>>>(cnt, boff, offsets);
  k_part<<<NPB, 256, 0, stream>>>(ei, cnt, ssrc, sdst, stage);
  k_place<<<NBKT, 256, 0, stream>>>(boff, stage, offsets, csr);
  k_agg<<<((size_t)NN * 16 + 255) / 256, 256, 0, stream>>>(offsets, csr, h16, out);
}

// Round 5
// 141.057 us; speedup vs baseline: 4.8973x; 2.7317x over previous
//
#include <hip/hip_runtime.h>
#include <math.h>

#define NN 100000          // nodes
#define NE 1600000         // edges
#define NBKT 391           // buckets of 256 nodes: (NN+255)/256
#define EPB 4096           // edges per partition block
#define NPB ((NE + EPB - 1) / EPB)        // 391 partition blocks
#define TOTC (NBKT * NPB)                 // 152,881 scanned cells
#define SBLK 2048                         // scan elems per block
#define NSB ((TOTC + SBLK - 1) / SBLK)    // 75 scan blocks
#define LBUF 6144          // per-bucket LDS entry cap (mean 4092, +32 sigma)

typedef unsigned int uint;
typedef unsigned short ushort;

static __device__ __forceinline__ ushort f2bf(float f) {
  uint u = __float_as_uint(f);
  uint r = (u + 0x7fffu + ((u >> 16) & 1u)) >> 16;   // RNE
  return (ushort)r;
}
static __device__ __forceinline__ float bf2f(ushort v) {
  return __uint_as_float((uint)v << 16);
}

// ---------------- Kernel A: h = x @ W^T (bf16 out), fused s_src/s_dst ----
__global__ __launch_bounds__(256, 2) void k_h(
    const float* __restrict__ x, const float* __restrict__ W,
    const float* __restrict__ a_src, const float* __restrict__ a_dst,
    ushort* __restrict__ h16, float* __restrict__ ssrc, float* __restrict__ sdst)
{
  __shared__ float4 xs4[64 * 32];
  __shared__ float4 ws4[64 * 32];
  const int tid = threadIdx.x;
  const int ty = tid >> 4;
  const int tx = tid & 15;
  const int base = blockIdx.x * 64;

  const float4* x4 = (const float4*)x;
  const float4* W4 = (const float4*)W;
#pragma unroll
  for (int q = 0; q < 8; ++q) {
    int f = q * 256 + tid;
    int row = f >> 5, c4 = f & 31;
    int sw = row * 32 + (c4 ^ (row & 7));
    ws4[sw] = W4[f];
    int node = base + row;
    float4 xv = make_float4(0.f, 0.f, 0.f, 0.f);
    if (node < NN) xv = x4[node * 32 + c4];
    xs4[sw] = xv;
  }
  __syncthreads();

  float acc[4][4];
#pragma unroll
  for (int i = 0; i < 4; ++i)
#pragma unroll
    for (int j = 0; j < 4; ++j) acc[i][j] = 0.f;

  const int axor = ty & 7, bxor = tx & 7;
  int arow[4], brow[4];
#pragma unroll
  for (int i = 0; i < 4; ++i) { arow[i] = (ty + 16 * i) * 32; brow[i] = (tx + 16 * i) * 32; }

#pragma unroll 8
  for (int k4 = 0; k4 < 32; ++k4) {
    float4 a4[4], b4[4];
#pragma unroll
    for (int i = 0; i < 4; ++i) a4[i] = xs4[arow[i] + (k4 ^ axor)];
#pragma unroll
    for (int j = 0; j < 4; ++j) b4[j] = ws4[brow[j] + (k4 ^ bxor)];
#pragma unroll
    for (int i = 0; i < 4; ++i)
#pragma unroll
      for (int j = 0; j < 4; ++j)
        acc[i][j] += a4[i].x * b4[j].x + a4[i].y * b4[j].y
                   + a4[i].z * b4[j].z + a4[i].w * b4[j].w;
  }

  float as[4], ad[4];
#pragma unroll
  for (int j = 0; j < 4; ++j) { as[j] = a_src[tx + 16 * j]; ad[j] = a_dst[tx + 16 * j]; }
#pragma unroll
  for (int i = 0; i < 4; ++i) {
    float ps = acc[i][0] * as[0] + acc[i][1] * as[1] + acc[i][2] * as[2] + acc[i][3] * as[3];
    float pd = acc[i][0] * ad[0] + acc[i][1] * ad[1] + acc[i][2] * ad[2] + acc[i][3] * ad[3];
#pragma unroll
    for (int m = 1; m < 16; m <<= 1) { ps += __shfl_xor(ps, m); pd += __shfl_xor(pd, m); }
    int node = base + ty + 16 * i;
    if (tx == 0 && node < NN) { ssrc[node] = ps; sdst[node] = pd; }
  }
#pragma unroll
  for (int i = 0; i < 4; ++i) {
    int node = base + ty + 16 * i;
    if (node < NN) {
#pragma unroll
      for (int j = 0; j < 4; ++j) h16[node * 64 + tx + 16 * j] = f2bf(acc[i][j]);
    }
  }
}

// ---------------- per-block bucket histogram (no global atomics) ----------------
__global__ __launch_bounds__(256) void k_hist(const int* __restrict__ ei,
                                              int* __restrict__ cnt)
{
  __shared__ int hh[NBKT];
  int t = threadIdx.x, blk = blockIdx.x;
  for (int i = t; i < NBKT; i += 256) hh[i] = 0;
  __syncthreads();
  int base = blk * EPB;
#pragma unroll
  for (int q = 0; q < EPB / 256; ++q) {
    int e = base + q * 256 + t;
    if (e < NE) atomicAdd(&hh[ei[NE + e] >> 8], 1);
  }
  __syncthreads();
  for (int i = t; i < NBKT; i += 256) cnt[i * NPB + blk] = hh[i];
}

// ---------------- 3-pass grid-parallel exclusive scan of cnt[TOTC] --------------
// Pass A: per-block sums. Block = 256 threads x 8 elems (int4 x2).
__global__ __launch_bounds__(256) void k_scanA(const int* __restrict__ cnt,
                                               int* __restrict__ partials)
{
  __shared__ int sm[256];
  int t = threadIdx.x, b = blockIdx.x;
  const int4* c4 = (const int4*)(cnt + b * SBLK + t * 8);
  int4 u = c4[0], v = c4[1];
  sm[t] = u.x + u.y + u.z + u.w + v.x + v.y + v.z + v.w;
  __syncthreads();
  for (int s = 128; s > 0; s >>= 1) { if (t < s) sm[t] += sm[t + s]; __syncthreads(); }
  if (t == 0) partials[b] = sm[0];
}

// Pass B: scan the NSB partials (tiny, one block).
__global__ __launch_bounds__(128) void k_scanB(int* __restrict__ partials,
                                               int* __restrict__ boff,
                                               int* __restrict__ offsets)
{
  __shared__ int sm[128];
  int t = threadIdx.x;
  int v = (t < NSB) ? partials[t] : 0;
  sm[t] = v;
  __syncthreads();
  for (int off = 1; off < 128; off <<= 1) {
    int u = (t >= off) ? sm[t - off] : 0;
    __syncthreads();
    sm[t] += u;
    __syncthreads();
  }
  if (t < NSB) partials[t] = sm[t] - v;   // exclusive
  if (t == 0) { boff[NBKT] = NE; offsets[NN] = NE; }
}

// Pass C: write exclusive prefixes in place; emit boff at bucket starts.
__global__ __launch_bounds__(256) void k_scanC(int* __restrict__ cnt,
                                               const int* __restrict__ partials,
                                               int* __restrict__ boff)
{
  __shared__ int sm[256];
  int t = threadIdx.x, b = blockIdx.x;
  int base = b * SBLK + t * 8;
  int4* c4 = (int4*)(cnt + base);
  int4 u = c4[0], v = c4[1];
  int tot = u.x + u.y + u.z + u.w + v.x + v.y + v.z + v.w;
  sm[t] = tot;
  __syncthreads();
  for (int off = 1; off < 256; off <<= 1) {
    int w = (t >= off) ? sm[t - off] : 0;
    __syncthreads();
    sm[t] += w;
    __syncthreads();
  }
  int run = partials[b] + sm[t] - tot;
  int e[8] = {u.x, u.y, u.z, u.w, v.x, v.y, v.z, v.w};
  int ex[8];
#pragma unroll
  for (int k = 0; k < 8; ++k) { ex[k] = run; run += e[k]; }
#pragma unroll
  for (int k = 0; k < 8; ++k) {
    int idx = base + k;
    if (idx < TOTC && idx % NPB == 0) boff[idx / NPB] = ex[k];
  }
  c4[0] = make_int4(ex[0], ex[1], ex[2], ex[3]);
  c4[1] = make_int4(ex[4], ex[5], ex[6], ex[7]);
}

// ---------------- partition pass: LDS cursors, alpha computed inline ------------
__global__ __launch_bounds__(256) void k_part(const int* __restrict__ ei,
                                              const int* __restrict__ cnt,
                                              const float* __restrict__ ssrc,
                                              const float* __restrict__ sdst,
                                              int2* __restrict__ stage)
{
  __shared__ int cur[NBKT];
  int t = threadIdx.x, blk = blockIdx.x;
  for (int i = t; i < NBKT; i += 256) cur[i] = cnt[i * NPB + blk];
  __syncthreads();
  int base = blk * EPB;
#pragma unroll
  for (int q = 0; q < EPB / 256; ++q) {
    int e = base + q * 256 + t;
    if (e < NE) {
      int src = ei[e];
      int dst = ei[NE + e];
      int pos = atomicAdd(&cur[dst >> 8], 1);
      float v = ssrc[src] + sdst[dst];
      v = (v >= 0.f) ? v : 0.2f * v;           // LeakyReLU(0.2)
      v = fminf(fmaxf(v, -10.f), 10.f);        // clip
      stage[pos] = make_int2(src | ((dst & 255) << 24), __float_as_int(__expf(v)));
    }
  }
}

// ---------------- place: per-bucket node-sort in LDS, coalesced CSR out ---------
__global__ __launch_bounds__(256) void k_place(const int* __restrict__ boff,
                                               const int2* __restrict__ stage,
                                               int* __restrict__ offsets,
                                               int2* __restrict__ csr)
{
  __shared__ int2 lbuf[LBUF];
  __shared__ int cnt2[256];
  __shared__ int cur2[256];
  int b = blockIdx.x, t = threadIdx.x;
  int e_beg = boff[b], e_end = boff[b + 1];
  int m = e_end - e_beg;

  cnt2[t] = 0;
  __syncthreads();
  for (int i = t; i < m; i += 256)
    atomicAdd(&cnt2[((uint)stage[e_beg + i].x) >> 24], 1);
  __syncthreads();

  int v0 = cnt2[t];
  for (int off = 1; off < 256; off <<= 1) {
    int u = (t >= off) ? cnt2[t - off] : 0;
    __syncthreads();
    cnt2[t] += u;
    __syncthreads();
  }
  int excl = cnt2[t] - v0;
  cur2[t] = excl;
  int node = (b << 8) + t;
  if (node < NN) offsets[node] = e_beg + excl;
  __syncthreads();

  for (int i = t; i < m; i += 256) {
    int2 v = stage[e_beg + i];
    int dl = ((uint)v.x) >> 24;
    int slot = atomicAdd(&cur2[dl], 1);
    lbuf[slot] = make_int2(v.x & 0xFFFFFF, v.y);
  }
  __syncthreads();
  for (int i = t; i < m; i += 256) csr[e_beg + i] = lbuf[i];
}

// ---------------- aggregation: 16 lanes/node, 4 nodes/wave, unroll-4 ------------
__global__ __launch_bounds__(256) void k_agg(const int* __restrict__ offsets,
                                             const int2* __restrict__ csr,
                                             const ushort* __restrict__ h16,
                                             float* __restrict__ out)
{
  int t = blockIdx.x * 256 + threadIdx.x;
  int node = t >> 4;
  int l4 = t & 15;
  if (node >= NN) return;
  int beg = offsets[node];
  int end = offsets[node + 1];
  const uint2* h2 = (const uint2*)h16;
  float ax = 0.f, ay = 0.f, az = 0.f, aw = 0.f, den = 0.f;
  int last = end - 1;
  for (int j = beg; j < end; j += 4) {
    int2 e0 = csr[j];
    int2 e1 = csr[min(j + 1, last)];
    int2 e2 = csr[min(j + 2, last)];
    int2 e3 = csr[min(j + 3, last)];
    float a0 = __int_as_float(e0.y);
    float a1 = (j + 1 < end) ? __int_as_float(e1.y) : 0.f;
    float a2 = (j + 2 < end) ? __int_as_float(e2.y) : 0.f;
    float a3 = (j + 3 < end) ? __int_as_float(e3.y) : 0.f;
    uint2 q0 = h2[e0.x * 16 + l4];
    uint2 q1 = h2[e1.x * 16 + l4];
    uint2 q2 = h2[e2.x * 16 + l4];
    uint2 q3 = h2[e3.x * 16 + l4];
    den += (a0 + a1) + (a2 + a3);
    ax += a0 * bf2f((ushort)(q0.x & 0xffff)) + a1 * bf2f((ushort)(q1.x & 0xffff))
        + a2 * bf2f((ushort)(q2.x & 0xffff)) + a3 * bf2f((ushort)(q3.x & 0xffff));
    ay += a0 * bf2f((ushort)(q0.x >> 16)) + a1 * bf2f((ushort)(q1.x >> 16))
        + a2 * bf2f((ushort)(q2.x >> 16)) + a3 * bf2f((ushort)(q3.x >> 16));
    az += a0 * bf2f((ushort)(q0.y & 0xffff)) + a1 * bf2f((ushort)(q1.y & 0xffff))
        + a2 * bf2f((ushort)(q2.y & 0xffff)) + a3 * bf2f((ushort)(q3.y & 0xffff));
    aw += a0 * bf2f((ushort)(q0.y >> 16)) + a1 * bf2f((ushort)(q1.y >> 16))
        + a2 * bf2f((ushort)(q2.y >> 16)) + a3 * bf2f((ushort)(q3.y >> 16));
  }
  float inv = 1.f / (den + 1e-9f);
  float4 o;
  o.x = ax * inv; o.y = ay * inv; o.z = az * inv; o.w = aw * inv;
  ((float4*)out)[node * 16 + l4] = o;
}

extern "C" void kernel_launch(void* const* d_in, const int* in_sizes, int n_in,
                              void* d_out, int out_size, void* d_ws, size_t ws_size,
                              hipStream_t stream)
{
  const float* x     = (const float*)d_in[0];
  const int*   ei    = (const int*)d_in[1];
  const float* W     = (const float*)d_in[2];
  const float* a_src = (const float*)d_in[3];
  const float* a_dst = (const float*)d_in[4];
  float* out = (float*)d_out;

  char* p = (char*)d_ws;
  auto alloc = [&](size_t bytes) -> char* {
    char* r = p;
    p += (bytes + 255) & ~(size_t)255;
    return r;
  };
  ushort* h16    = (ushort*)alloc((size_t)NN * 64 * 2);
  float* ssrc    = (float*)alloc((size_t)NN * 4);
  float* sdst    = (float*)alloc((size_t)NN * 4);
  int*   offsets = (int*)alloc((size_t)(NN + 1) * 4);
  int*   cnt     = (int*)alloc((size_t)NSB * SBLK * 4);   // padded past TOTC
  int*   boff    = (int*)alloc((size_t)(NBKT + 1) * 4);
  int*   partials= (int*)alloc((size_t)NSB * 4);
  int2*  stage   = (int2*)alloc((size_t)NE * 8);
  int2*  csr     = (int2*)alloc((size_t)NE * 8);

  k_h<<<(NN + 63) / 64, 256, 0, stream>>>(x, W, a_src, a_dst, h16, ssrc, sdst);
  k_hist<<<NPB, 256, 0, stream>>>(ei, cnt);
  k_scanA<<<NSB, 256, 0, stream>>>(cnt, partials);
  k_scanB<<<1, 128, 0, stream>>>(partials, boff, offsets);
  k_scanC<<<NSB, 256, 0, stream>>>(cnt, partials, boff);
  k_part<<<NPB, 256, 0, stream>>>(ei, cnt, ssrc, sdst, stage);
  k_place<<<NBKT, 256, 0, stream>>>(boff, stage, offsets, csr);
  k_agg<<<((size_t)NN * 16 + 255) / 256, 256, 0, stream>>>(offsets, csr, h16, out);
}

// Round 6
// 116.645 us; speedup vs baseline: 5.9222x; 1.2093x over previous
//
#include <hip/hip_runtime.h>
#include <math.h>

#define NN 100000          // nodes
#define NE 1600000         // edges
#define NBKT 391           // buckets of 256 nodes: (NN+255)/256
#define EPB 4096           // edges per partition block
#define NPB ((NE + EPB - 1) / EPB)        // 391 partition blocks
#define TOTC (NBKT * NPB)                 // 152,881 scanned cells
#define SBLK 2048                         // scan elems per block
#define NSB ((TOTC + SBLK - 1) / SBLK)    // 75 scan blocks
#define LBUF 6144          // per-bucket LDS entry cap (mean 4092, +32 sigma)

typedef unsigned int uint;
typedef unsigned short ushort;
typedef __attribute__((ext_vector_type(8))) short bfx8;
typedef __attribute__((ext_vector_type(4))) float f32x4;

static __device__ __forceinline__ ushort f2bf(float f) {
  uint u = __float_as_uint(f);
  uint r = (u + 0x7fffu + ((u >> 16) & 1u)) >> 16;   // RNE
  return (ushort)r;
}
static __device__ __forceinline__ float bf2f(ushort v) {
  return __uint_as_float((uint)v << 16);
}

// ---------------- Kernel A: h = x @ W^T via bf16 MFMA, fused s_src/s_dst ----
// 128 nodes x 64 outs x K=128 per block; 4 waves, each 32x64 (2x4 16x16 tiles).
// LDS bf16 tiles, XOR-swizzled: row stride 256B would be 16-way conflict;
// byte ^= (row&7)<<4 spreads 8 rows across the 128B bank window (T2).
__global__ __launch_bounds__(256) void k_h(
    const float* __restrict__ x, const float* __restrict__ W,
    const float* __restrict__ a_src, const float* __restrict__ a_dst,
    ushort* __restrict__ h16, float* __restrict__ ssrc, float* __restrict__ sdst)
{
  __shared__ __align__(16) ushort xs[128 * 128];  // 32KB
  __shared__ __align__(16) ushort ws[64 * 128];   // 16KB
  const int t = threadIdx.x;
  const int base = blockIdx.x * 128;
  const float4* x4 = (const float4*)x;
  const float4* W4 = (const float4*)W;

  // stage x tile: 128 rows x 32 float4, fp32 -> bf16, swizzled
#pragma unroll
  for (int q = 0; q < 16; ++q) {
    int f = q * 256 + t;
    int row = f >> 5, c4 = f & 31;
    float4 v = make_float4(0.f, 0.f, 0.f, 0.f);
    if (base + row < NN) v = x4[(size_t)(base + row) * 32 + c4];
    ushort4 pk = make_ushort4(f2bf(v.x), f2bf(v.y), f2bf(v.z), f2bf(v.w));
    int byte = row * 256 + ((c4 * 8) ^ ((row & 7) << 4));
    *(ushort4*)((char*)xs + byte) = pk;
  }
  // stage W: 64 rows x 32 float4
#pragma unroll
  for (int q = 0; q < 8; ++q) {
    int f = q * 256 + t;
    int row = f >> 5, c4 = f & 31;
    float4 v = W4[f];
    ushort4 pk = make_ushort4(f2bf(v.x), f2bf(v.y), f2bf(v.z), f2bf(v.w));
    int byte = row * 256 + ((c4 * 8) ^ ((row & 7) << 4));
    *(ushort4*)((char*)ws + byte) = pk;
  }
  __syncthreads();

  const int wid = t >> 6;
  const int lane = t & 63;
  const int lg = lane >> 4;    // k-group (8 bf16 each) / C row group
  const int lr = lane & 15;    // A row / B col / C col

  f32x4 acc[2][4];
#pragma unroll
  for (int mg = 0; mg < 2; ++mg)
#pragma unroll
    for (int ng = 0; ng < 4; ++ng) acc[mg][ng] = (f32x4){0.f, 0.f, 0.f, 0.f};

#pragma unroll
  for (int ks = 0; ks < 4; ++ks) {
    int kb = ks * 64 + lg * 16;    // byte offset of this lane's 8 bf16 in a row
    bfx8 afr[2], bfr[4];
#pragma unroll
    for (int mg = 0; mg < 2; ++mg) {
      int row = wid * 32 + mg * 16 + lr;
      afr[mg] = *(const bfx8*)((const char*)xs + row * 256 + (kb ^ ((row & 7) << 4)));
    }
#pragma unroll
    for (int ng = 0; ng < 4; ++ng) {
      int row = ng * 16 + lr;
      bfr[ng] = *(const bfx8*)((const char*)ws + row * 256 + (kb ^ ((row & 7) << 4)));
    }
#pragma unroll
    for (int mg = 0; mg < 2; ++mg)
#pragma unroll
      for (int ng = 0; ng < 4; ++ng)
        acc[mg][ng] = __builtin_amdgcn_mfma_f32_16x16x32_bf16(afr[mg], bfr[ng], acc[mg][ng], 0, 0, 0);
  }

  // epilogue: fused s_src/s_dst (reduce over the 16 col-lanes) + bf16 h write
  float as_[4], ad_[4];
#pragma unroll
  for (int ng = 0; ng < 4; ++ng) { as_[ng] = a_src[ng * 16 + lr]; ad_[ng] = a_dst[ng * 16 + lr]; }
#pragma unroll
  for (int mg = 0; mg < 2; ++mg) {
#pragma unroll
    for (int r = 0; r < 4; ++r) {
      int node = base + wid * 32 + mg * 16 + lg * 4 + r;
      float ps = 0.f, pd = 0.f;
#pragma unroll
      for (int ng = 0; ng < 4; ++ng) { ps += acc[mg][ng][r] * as_[ng]; pd += acc[mg][ng][r] * ad_[ng]; }
#pragma unroll
      for (int m = 1; m < 16; m <<= 1) { ps += __shfl_xor(ps, m); pd += __shfl_xor(pd, m); }
      if (lr == 0 && node < NN) { ssrc[node] = ps; sdst[node] = pd; }
      if (node < NN) {
#pragma unroll
        for (int ng = 0; ng < 4; ++ng)
          h16[(size_t)node * 64 + ng * 16 + lr] = f2bf(acc[mg][ng][r]);
      }
    }
  }
}

// ---------------- per-block bucket histogram (no global atomics) ----------------
__global__ __launch_bounds__(256) void k_hist(const int* __restrict__ ei,
                                              int* __restrict__ cnt)
{
  __shared__ int hh[NBKT];
  int t = threadIdx.x, blk = blockIdx.x;
  for (int i = t; i < NBKT; i += 256) hh[i] = 0;
  __syncthreads();
  int base = blk * EPB;
#pragma unroll
  for (int q = 0; q < EPB / 256; ++q) {
    int e = base + q * 256 + t;
    if (e < NE) atomicAdd(&hh[ei[NE + e] >> 8], 1);
  }
  __syncthreads();
  for (int i = t; i < NBKT; i += 256) cnt[i * NPB + blk] = hh[i];
}

// ---------------- 3-pass grid-parallel exclusive scan of cnt[TOTC] --------------
__global__ __launch_bounds__(256) void k_scanA(const int* __restrict__ cnt,
                                               int* __restrict__ partials)
{
  __shared__ int sm[256];
  int t = threadIdx.x, b = blockIdx.x;
  const int4* c4 = (const int4*)(cnt + b * SBLK + t * 8);
  int4 u = c4[0], v = c4[1];
  sm[t] = u.x + u.y + u.z + u.w + v.x + v.y + v.z + v.w;
  __syncthreads();
  for (int s = 128; s > 0; s >>= 1) { if (t < s) sm[t] += sm[t + s]; __syncthreads(); }
  if (t == 0) partials[b] = sm[0];
}

__global__ __launch_bounds__(128) void k_scanB(int* __restrict__ partials,
                                               int* __restrict__ boff,
                                               int* __restrict__ offsets)
{
  __shared__ int sm[128];
  int t = threadIdx.x;
  int v = (t < NSB) ? partials[t] : 0;
  sm[t] = v;
  __syncthreads();
  for (int off = 1; off < 128; off <<= 1) {
    int u = (t >= off) ? sm[t - off] : 0;
    __syncthreads();
    sm[t] += u;
    __syncthreads();
  }
  if (t < NSB) partials[t] = sm[t] - v;   // exclusive
  if (t == 0) { boff[NBKT] = NE; offsets[NN] = NE; }
}

__global__ __launch_bounds__(256) void k_scanC(int* __restrict__ cnt,
                                               const int* __restrict__ partials,
                                               int* __restrict__ boff)
{
  __shared__ int sm[256];
  int t = threadIdx.x, b = blockIdx.x;
  int base = b * SBLK + t * 8;
  int4* c4 = (int4*)(cnt + base);
  int4 u = c4[0], v = c4[1];
  int tot = u.x + u.y + u.z + u.w + v.x + v.y + v.z + v.w;
  sm[t] = tot;
  __syncthreads();
  for (int off = 1; off < 256; off <<= 1) {
    int w = (t >= off) ? sm[t - off] : 0;
    __syncthreads();
    sm[t] += w;
    __syncthreads();
  }
  int run = partials[b] + sm[t] - tot;
  int e[8] = {u.x, u.y, u.z, u.w, v.x, v.y, v.z, v.w};
  int ex[8];
#pragma unroll
  for (int k = 0; k < 8; ++k) { ex[k] = run; run += e[k]; }
#pragma unroll
  for (int k = 0; k < 8; ++k) {
    int idx = base + k;
    if (idx < TOTC && idx % NPB == 0) boff[idx / NPB] = ex[k];
  }
  c4[0] = make_int4(ex[0], ex[1], ex[2], ex[3]);
  c4[1] = make_int4(ex[4], ex[5], ex[6], ex[7]);
}

// ---------------- partition pass: LDS cursors, alpha computed inline ------------
__global__ __launch_bounds__(256) void k_part(const int* __restrict__ ei,
                                              const int* __restrict__ cnt,
                                              const float* __restrict__ ssrc,
                                              const float* __restrict__ sdst,
                                              int2* __restrict__ stage)
{
  __shared__ int cur[NBKT];
  int t = threadIdx.x, blk = blockIdx.x;
  for (int i = t; i < NBKT; i += 256) cur[i] = cnt[i * NPB + blk];
  __syncthreads();
  int base = blk * EPB;
#pragma unroll
  for (int q = 0; q < EPB / 256; ++q) {
    int e = base + q * 256 + t;
    if (e < NE) {
      int src = ei[e];
      int dst = ei[NE + e];
      int pos = atomicAdd(&cur[dst >> 8], 1);
      float v = ssrc[src] + sdst[dst];
      v = (v >= 0.f) ? v : 0.2f * v;           // LeakyReLU(0.2)
      v = fminf(fmaxf(v, -10.f), 10.f);        // clip
      stage[pos] = make_int2(src | ((dst & 255) << 24), __float_as_int(__expf(v)));
    }
  }
}

// ---------------- place: per-bucket node-sort in LDS, coalesced CSR out ---------
__global__ __launch_bounds__(256) void k_place(const int* __restrict__ boff,
                                               const int2* __restrict__ stage,
                                               int* __restrict__ offsets,
                                               int2* __restrict__ csr)
{
  __shared__ int2 lbuf[LBUF];
  __shared__ int cnt2[256];
  __shared__ int cur2[256];
  int b = blockIdx.x, t = threadIdx.x;
  int e_beg = boff[b], e_end = boff[b + 1];
  int m = e_end - e_beg;

  cnt2[t] = 0;
  __syncthreads();
  for (int i = t; i < m; i += 256)
    atomicAdd(&cnt2[((uint)stage[e_beg + i].x) >> 24], 1);
  __syncthreads();

  int v0 = cnt2[t];
  for (int off = 1; off < 256; off <<= 1) {
    int u = (t >= off) ? cnt2[t - off] : 0;
    __syncthreads();
    cnt2[t] += u;
    __syncthreads();
  }
  int excl = cnt2[t] - v0;
  cur2[t] = excl;
  int node = (b << 8) + t;
  if (node < NN) offsets[node] = e_beg + excl;
  __syncthreads();

  for (int i = t; i < m; i += 256) {
    int2 v = stage[e_beg + i];
    int dl = ((uint)v.x) >> 24;
    int slot = atomicAdd(&cur2[dl], 1);
    lbuf[slot] = make_int2(v.x & 0xFFFFFF, v.y);
  }
  __syncthreads();
  for (int i = t; i < m; i += 256) csr[e_beg + i] = lbuf[i];
}

// ---------------- aggregation: 16 lanes/node, 4 nodes/wave, unroll-4 ------------
__global__ __launch_bounds__(256) void k_agg(const int* __restrict__ offsets,
                                             const int2* __restrict__ csr,
                                             const ushort* __restrict__ h16,
                                             float* __restrict__ out)
{
  int t = blockIdx.x * 256 + threadIdx.x;
  int node = t >> 4;
  int l4 = t & 15;
  if (node >= NN) return;
  int beg = offsets[node];
  int end = offsets[node + 1];
  const uint2* h2 = (const uint2*)h16;
  float ax = 0.f, ay = 0.f, az = 0.f, aw = 0.f, den = 0.f;
  int last = end - 1;
  for (int j = beg; j < end; j += 4) {
    int2 e0 = csr[j];
    int2 e1 = csr[min(j + 1, last)];
    int2 e2 = csr[min(j + 2, last)];
    int2 e3 = csr[min(j + 3, last)];
    float a0 = __int_as_float(e0.y);
    float a1 = (j + 1 < end) ? __int_as_float(e1.y) : 0.f;
    float a2 = (j + 2 < end) ? __int_as_float(e2.y) : 0.f;
    float a3 = (j + 3 < end) ? __int_as_float(e3.y) : 0.f;
    uint2 q0 = h2[e0.x * 16 + l4];
    uint2 q1 = h2[e1.x * 16 + l4];
    uint2 q2 = h2[e2.x * 16 + l4];
    uint2 q3 = h2[e3.x * 16 + l4];
    den += (a0 + a1) + (a2 + a3);
    ax += a0 * bf2f((ushort)(q0.x & 0xffff)) + a1 * bf2f((ushort)(q1.x & 0xffff))
        + a2 * bf2f((ushort)(q2.x & 0xffff)) + a3 * bf2f((ushort)(q3.x & 0xffff));
    ay += a0 * bf2f((ushort)(q0.x >> 16)) + a1 * bf2f((ushort)(q1.x >> 16))
        + a2 * bf2f((ushort)(q2.x >> 16)) + a3 * bf2f((ushort)(q3.x >> 16));
    az += a0 * bf2f((ushort)(q0.y & 0xffff)) + a1 * bf2f((ushort)(q1.y & 0xffff))
        + a2 * bf2f((ushort)(q2.y & 0xffff)) + a3 * bf2f((ushort)(q3.y & 0xffff));
    aw += a0 * bf2f((ushort)(q0.y >> 16)) + a1 * bf2f((ushort)(q1.y >> 16))
        + a2 * bf2f((ushort)(q2.y >> 16)) + a3 * bf2f((ushort)(q3.y >> 16));
  }
  float inv = 1.f / (den + 1e-9f);
  float4 o;
  o.x = ax * inv; o.y = ay * inv; o.z = az * inv; o.w = aw * inv;
  ((float4*)out)[node * 16 + l4] = o;
}

extern "C" void kernel_launch(void* const* d_in, const int* in_sizes, int n_in,
                              void* d_out, int out_size, void* d_ws, size_t ws_size,
                              hipStream_t stream)
{
  const float* x     = (const float*)d_in[0];
  const int*   ei    = (const int*)d_in[1];
  const float* W     = (const float*)d_in[2];
  const float* a_src = (const float*)d_in[3];
  const float* a_dst = (const float*)d_in[4];
  float* out = (float*)d_out;

  char* p = (char*)d_ws;
  auto alloc = [&](size_t bytes) -> char* {
    char* r = p;
    p += (bytes + 255) & ~(size_t)255;
    return r;
  };
  ushort* h16    = (ushort*)alloc((size_t)NN * 64 * 2);
  float* ssrc    = (float*)alloc((size_t)NN * 4);
  float* sdst    = (float*)alloc((size_t)NN * 4);
  int*   offsets = (int*)alloc((size_t)(NN + 1) * 4);
  int*   cnt     = (int*)alloc((size_t)NSB * SBLK * 4);   // padded past TOTC
  int*   boff    = (int*)alloc((size_t)(NBKT + 1) * 4);
  int*   partials= (int*)alloc((size_t)NSB * 4);
  int2*  stage   = (int2*)alloc((size_t)NE * 8);
  int2*  csr     = (int2*)alloc((size_t)NE * 8);

  k_h<<<(NN + 127) / 128, 256, 0, stream>>>(x, W, a_src, a_dst, h16, ssrc, sdst);
  k_hist<<<NPB, 256, 0, stream>>>(ei, cnt);
  k_scanA<<<NSB, 256, 0, stream>>>(cnt, partials);
  k_scanB<<<1, 128, 0, stream>>>(partials, boff, offsets);
  k_scanC<<<NSB, 256, 0, stream>>>(cnt, partials, boff);
  k_part<<<NPB, 256, 0, stream>>>(ei, cnt, ssrc, sdst, stage);
  k_place<<<NBKT, 256, 0, stream>>>(boff, stage, offsets, csr);
  k_agg<<<((size_t)NN * 16 + 255) / 256, 256, 0, stream>>>(offsets, csr, h16, out);
}